// Round 2
// 762.985 us; speedup vs baseline: 1.1699x; 1.1699x over previous
//
#include <hip/hip_runtime.h>
#include <hip/hip_bf16.h>
#include <cstdint>
#include <cstddef>

#define N_MOLS 256
#define NN     8192
#define SDIM_  256
#define NAF_   16
#define LAYERS_ 5

typedef __attribute__((ext_vector_type(8)))  short bf16x8;
typedef __attribute__((ext_vector_type(16))) float f32x16;

__device__ __forceinline__ float silu_f(float x) {
    return x / (1.f + __expf(-x));
}
__device__ __forceinline__ short bfc(float f) {
    __hip_bfloat16 h = __float2bfloat16(f);
    return __builtin_bit_cast(short, h);
}
__device__ __forceinline__ float bf2f(short h) {
    union { uint32_t u; float f; } v; v.u = ((uint32_t)(unsigned short)h) << 16; return v.f;
}
#define ONEBF ((short)0x3F80)

// ---------------------------------------------------------------------------
// weight image offsets (in shorts, within wb)
// ---------------------------------------------------------------------------
#define OFF_T1    0         // 5 * 512*256   : W1ab^T  [l][j2][k]
#define OFF_W2ST  655360    // 5 * 256*256   : W2s^T   [l][n][k]
#define OFF_WH1T  983040    // 256*256       : Wh1^T   [n][k]
#define OFF_WE1T  1048576   // 128*256       : We1^T   [n][k]
#define OFF_W1CG  1081344   // 5 * 256*32    : W1c slot groups [l][j][w]
#define OFF_W1DA  1122304   // 5 * 2*256    : W1 d/a rows
#define OFF_W2P   1124864   // 5 * 256       : W2 col 320
#define OFF_W2EI  1126144   // 5 * 8192      : sW2e fragment image
#define OFF_WE1CG 1167104   // 128*32        : We1c slot groups
#define OFF_WD    1171200   // 128           : We1 row 288
#define OFF_WE2I  1171328   // 8*64*8        : We2 fragment image
#define W_TOTAL   1175424

// ---------------------------------------------------------------------------
// one-shot weight conversion / transpose / swizzle into bf16 images
// ---------------------------------------------------------------------------
__global__ __launch_bounds__(256) void prep_weights(
    const float* __restrict__ gW1, const float* __restrict__ gW2,
    const float* __restrict__ Wh1, const float* __restrict__ We1,
    const float* __restrict__ We2, short* __restrict__ wb)
{
    for (int o = blockIdx.x * 256 + threadIdx.x; o < W_TOTAL; o += gridDim.x * 256) {
        float v;
        if (o < OFF_W2ST) {                       // T1 [l][j2<512][k<256]
            const int l = o >> 17, r = o & 131071;
            const int j2 = r >> 8, k = r & 255;
            v = gW1[(size_t)l * 139776 + (size_t)((j2 >> 8) * 256 + k) * 256 + (j2 & 255)];
        } else if (o < OFF_WH1T) {                // W2sT [l][n][k]
            const int q = o - OFF_W2ST;
            const int l = q >> 16, r = q & 65535;
            const int n = r >> 8, k = r & 255;
            v = gW2[(size_t)l * 90368 + (size_t)k * 353 + n];
        } else if (o < OFF_WE1T) {                // Wh1T [n][k]
            const int q = o - OFF_WH1T;
            v = Wh1[(size_t)(q & 255) * 256 + (q >> 8)];
        } else if (o < OFF_W1CG) {                // We1T [n][k]
            const int q = o - OFF_WE1T;
            v = We1[(size_t)(q & 255) * 128 + (q >> 8)];
        } else if (o < OFF_W1DA) {                // W1cG [l][j][w]: w = g*8+kk, k = 512+w
            const int q = o - OFF_W1CG;
            const int l = q >> 13, r = q & 8191;
            const int j = r >> 5, w = r & 31;
            v = gW1[(size_t)l * 139776 + (size_t)(512 + w) * 256 + j];
        } else if (o < OFF_W2P) {                 // W1da [l][d][j]
            const int q = o - OFF_W1DA;
            const int l = q >> 9, r = q & 511;
            v = gW1[(size_t)l * 139776 + (size_t)(544 + (r >> 8)) * 256 + (r & 255)];
        } else if (o < OFF_W2EI) {                // W2p [l][j]
            const int q = o - OFF_W2P;
            v = gW2[(size_t)(q >> 8) * 90368 + (size_t)(q & 255) * 353 + 320];
        } else if (o < OFF_WE1CG) {               // W2e fragment image [l][idx]
            const int q = o - OFF_W2EI;
            const int l = q >> 13, r = q & 8191;
            const int kk = r >> 9, lanei = (r >> 3) & 63, jj = r & 7;
            const int j = kk * 16 + (lanei >> 5) * 8 + jj;
            v = gW2[(size_t)l * 90368 + (size_t)j * 353 + 321 + (lanei & 31)];
        } else if (o < OFF_WD) {                  // We1cG [j][w]: k = 256+w
            const int q = o - OFF_WE1CG;
            v = We1[(size_t)(256 + (q & 31)) * 128 + (q >> 5)];
        } else if (o < OFF_WE2I) {                // Wd [j]
            v = We1[288 * 128 + (o - OFF_WD)];
        } else {                                  // We2 fragment image
            const int q = o - OFF_WE2I;
            const int kk = q >> 9, lanei = (q >> 3) & 63, jj = q & 7;
            const int c = lanei & 31;
            v = (c < 5) ? We2[(size_t)(kk * 16 + (lanei >> 5) * 8 + jj) * 5 + c] : 0.f;
        }
        wb[o] = bfc(v);
    }
}

// ---------------------------------------------------------------------------
// node init, 1 block per molecule: h = [x|z]@Wam+bam; s, sbf, pos
// ---------------------------------------------------------------------------
__global__ __launch_bounds__(256) void node_init2(
    const float* __restrict__ x, const float* __restrict__ z,
    const float* __restrict__ rot, const float* __restrict__ Wam,
    const float* __restrict__ bam, float* __restrict__ s,
    short* __restrict__ sbf, float* __restrict__ pos)
{
    const int mol = blockIdx.x, t = threadIdx.x;
    __shared__ __align__(16) float xz[32][80];
    __shared__ float praw[32][3];
    for (int idx = t; idx < 32 * 80; idx += 256) {
        const int i = idx / 80, k = idx % 80;
        xz[i][k] = (k < 16) ? x[(size_t)(mol * 32 + i) * 16 + k]
                            : z[(size_t)(mol * 32 + i) * 64 + (k - 16)];
    }
    __syncthreads();
    float acc[32];
    #pragma unroll
    for (int i = 0; i < 32; ++i) acc[i] = 0.f;
    for (int k0 = 0; k0 < 80; k0 += 4) {
        const float w0 = Wam[(k0 + 0) * 259 + t];
        const float w1 = Wam[(k0 + 1) * 259 + t];
        const float w2 = Wam[(k0 + 2) * 259 + t];
        const float w3 = Wam[(k0 + 3) * 259 + t];
        #pragma unroll
        for (int i = 0; i < 32; ++i) {
            const float4 xv = *(const float4*)&xz[i][k0];
            acc[i] += xv.x * w0 + xv.y * w1 + xv.z * w2 + xv.w * w3;
        }
    }
    const float bv = bam[t];
    #pragma unroll
    for (int i = 0; i < 32; ++i) {
        const float v = acc[i] + bv;
        s[(size_t)(mol * 32 + i) * 256 + t] = v;
        sbf[(size_t)(mol * 32 + i) * 256 + t] = bfc(v);
    }
    if (t < 96) {
        const int i = t / 3, c = t % 3;
        float a2 = bam[256 + c];
        for (int k = 0; k < 80; ++k) a2 += xz[i][k] * Wam[k * 259 + 256 + c];
        praw[i][c] = a2;
    }
    __syncthreads();
    if (t < 96) {
        const int i = t / 3, c = t % 3;
        float p = 0.f;
        for (int jj = 0; jj < 3; ++jj) p += rot[mol * 9 + c * 3 + jj] * praw[i][jj];
        pos[(size_t)(mol * 32 + i) * 3 + c] = p;
    }
}

// ---------------------------------------------------------------------------
// edge feature init (bf16 out), tgt-major: e[((mol*32+n)*31+rr)*32+c]
// ---------------------------------------------------------------------------
__global__ __launch_bounds__(256) void edge_init2(
    const float* __restrict__ ea, const float* __restrict__ Wbm,
    const float* __restrict__ bbm, short* __restrict__ ebuf)
{
    const int tile = blockIdx.x;
    const int mol = tile >> 5, n = tile & 31;
    const int t = threadIdx.x;
    for (int i = t; i < 31 * 32; i += 256) {
        const int rr = i >> 5, c = i & 31;
        const int s_ = rr + (rr >= n ? 1 : 0);
        const int ge = (mol * 32 + s_) * 31 + (n - (n > s_ ? 1 : 0));
        float acc = bbm[c];
        #pragma unroll
        for (int k = 0; k < 5; ++k) acc += ea[(size_t)ge * 5 + k] * Wbm[k * 32 + c];
        ebuf[(size_t)tile * 31 * 32 + i] = bfc(acc);
    }
}

// ---------------------------------------------------------------------------
// bf16 MFMA GEMM, A bf16 [m][k], B bf16 pre-transposed [n][k].
// C = act(alpha*(A@B)+bias) (+= if ACCUM); SBF also emits bf16 copy of C.
// POSTAIL: blocks (x==1, y<48) do pos += pd/31.
// ---------------------------------------------------------------------------
template<int ACT, int ACCUM, int POSTAIL, int OUTBF, int SBF>
__global__ __launch_bounds__(256) void gemm_mfma(
    const short* __restrict__ A, const short* __restrict__ BT,
    void* __restrict__ Cv, const float* __restrict__ bias,
    int K, int N, float alpha,
    float* __restrict__ pos, const float* __restrict__ pd,
    short* __restrict__ sbfo)
{
    const int n0 = blockIdx.x * 64, m0 = blockIdx.y * 128;
    const int t = threadIdx.x;
    const int wave = t >> 6, lane = t & 63;
    const int l = lane & 31, half = lane >> 5;
    const int wm = wave & 1, wn = wave >> 1;
    __shared__ __align__(16) short sA[128][40];
    __shared__ __align__(16) short sBt[64][40];
    f32x16 acc0 = {}, acc1 = {};
    const int mA = t >> 1, koA = (t & 1) * 16;
    const int nB = t & 63, kqB = (t >> 6) * 8;
    for (int k0 = 0; k0 < K; k0 += 32) {
        {
            const short* ap = A + (size_t)(m0 + mA) * K + k0 + koA;
            *(bf16x8*)&sA[mA][koA]     = *(const bf16x8*)(ap);
            *(bf16x8*)&sA[mA][koA + 8] = *(const bf16x8*)(ap + 8);
        }
        {
            const short* bp = BT + (size_t)(n0 + nB) * K + k0 + kqB;
            *(bf16x8*)&sBt[nB][kqB] = *(const bf16x8*)bp;
        }
        __syncthreads();
        #pragma unroll
        for (int ks = 0; ks < 2; ++ks) {
            const bf16x8 bfrag = *(const bf16x8*)&sBt[wn * 32 + l][ks * 16 + half * 8];
            const bf16x8 afr0  = *(const bf16x8*)&sA[wm * 64 + l][ks * 16 + half * 8];
            const bf16x8 afr1  = *(const bf16x8*)&sA[wm * 64 + 32 + l][ks * 16 + half * 8];
            acc0 = __builtin_amdgcn_mfma_f32_32x32x16_bf16(afr0, bfrag, acc0, 0,0,0);
            acc1 = __builtin_amdgcn_mfma_f32_32x32x16_bf16(afr1, bfrag, acc1, 0,0,0);
        }
        __syncthreads();
    }
    const int n = n0 + wn * 32 + l;
    const float bv = bias ? bias[n] : 0.f;
    #pragma unroll
    for (int r = 0; r < 16; ++r) {
        const int row = (r & 3) + 8 * (r >> 2) + 4 * half;
        #pragma unroll
        for (int h = 0; h < 2; ++h) {
            const int m = m0 + wm * 64 + h * 32 + row;
            float v = alpha * (h ? acc1[r] : acc0[r]) + bv;
            if (ACT) v = silu_f(v);
            if (OUTBF) {
                ((short*)Cv)[(size_t)m * N + n] = bfc(v);
            } else {
                float* cp = (float*)Cv + (size_t)m * N + n;
                const float nv = ACCUM ? (*cp + v) : v;
                *cp = nv;
                if (SBF) sbfo[(size_t)m * N + n] = bfc(nv);
            }
        }
    }
    if (POSTAIL && blockIdx.x == 1 && blockIdx.y < 48) {
        const int i = (blockIdx.y * 256 + t) * 2;
        pos[i]     += pd[i]     * (1.f / 31.f);
        pos[i + 1] += pd[i + 1] * (1.f / 31.f);
    }
}

// ---------------------------------------------------------------------------
// Dual GEMM: SA = sbf@W1a, SB = sbf@W1b (bf16 out), B from T1 images.
// ---------------------------------------------------------------------------
__global__ __launch_bounds__(256) void gemm_dual2(
    const short* __restrict__ A, const short* __restrict__ T1l,
    short* __restrict__ C0, short* __restrict__ C1)
{
    const int K = 256, N = 256;
    const int sel = blockIdx.x >> 2;
    short* C = sel ? C1 : C0;
    const int n0 = (blockIdx.x & 3) * 64, m0 = blockIdx.y * 128;
    const int bRow0 = sel * 256 + n0;
    const int t = threadIdx.x;
    const int wave = t >> 6, lane = t & 63;
    const int l = lane & 31, half = lane >> 5;
    const int wm = wave & 1, wn = wave >> 1;
    __shared__ __align__(16) short sA[128][40];
    __shared__ __align__(16) short sBt[64][40];
    f32x16 acc0 = {}, acc1 = {};
    const int mA = t >> 1, koA = (t & 1) * 16;
    const int nB = t & 63, kqB = (t >> 6) * 8;
    for (int k0 = 0; k0 < K; k0 += 32) {
        {
            const short* ap = A + (size_t)(m0 + mA) * K + k0 + koA;
            *(bf16x8*)&sA[mA][koA]     = *(const bf16x8*)(ap);
            *(bf16x8*)&sA[mA][koA + 8] = *(const bf16x8*)(ap + 8);
        }
        {
            const short* bp = T1l + (size_t)(bRow0 + nB) * K + k0 + kqB;
            *(bf16x8*)&sBt[nB][kqB] = *(const bf16x8*)bp;
        }
        __syncthreads();
        #pragma unroll
        for (int ks = 0; ks < 2; ++ks) {
            const bf16x8 bfrag = *(const bf16x8*)&sBt[wn * 32 + l][ks * 16 + half * 8];
            const bf16x8 afr0  = *(const bf16x8*)&sA[wm * 64 + l][ks * 16 + half * 8];
            const bf16x8 afr1  = *(const bf16x8*)&sA[wm * 64 + 32 + l][ks * 16 + half * 8];
            acc0 = __builtin_amdgcn_mfma_f32_32x32x16_bf16(afr0, bfrag, acc0, 0,0,0);
            acc1 = __builtin_amdgcn_mfma_f32_32x32x16_bf16(afr1, bfrag, acc1, 0,0,0);
        }
        __syncthreads();
    }
    const int n = n0 + wn * 32 + l;
    #pragma unroll
    for (int r = 0; r < 16; ++r) {
        const int row = (r & 3) + 8 * (r >> 2) + 4 * half;
        C[(size_t)(m0 + wm * 64 + row) * N + n]      = bfc(acc0[r]);
        C[(size_t)(m0 + wm * 64 + 32 + row) * N + n] = bfc(acc1[r]);
    }
}

// ---------------------------------------------------------------------------
// MFMA edge kernel. Grid 512 (2 blocks/mol), 512 thr (8 waves).
// Staging from pre-swizzled bf16 images; W2e fragments direct from global.
// ---------------------------------------------------------------------------
__global__ __launch_bounds__(512) void edge_mfma(
    const short* __restrict__ SA, const short* __restrict__ SB,
    const float* __restrict__ pos, short* __restrict__ ebuf,
    const short* __restrict__ W1cG, const short* __restrict__ W1daP,
    const short* __restrict__ W2pP, const short* __restrict__ W2eimg,
    const float* __restrict__ b1, const float* __restrict__ b2,
    short* __restrict__ Hbuf, float* __restrict__ pdelta)
{
    const int blk = blockIdx.x;
    const int mol = blk >> 1;
    const int nbase = (blk & 1) * 16;
    const int t = threadIdx.x;
    const int wave = t >> 6, lane = t & 63;
    const int l = lane & 31, half = lane >> 5;
    const int node0 = mol * 32;

    __shared__ __align__(16) short sBg[256][72];    // 36 KB
    __shared__ __align__(16) short sHdn[8][32][40]; // 20 KB
    __shared__ float sPosS[32][4];
    __shared__ __align__(16) short sW1da[2][256];
    __shared__ __align__(16) short sW2p[256];
    __shared__ float sP[8][32];

    {   // k0..31 = W1c from pre-swizzled image: 2 x bf16x8 (16B) per thread
        const int j = t & 255, gh = t >> 8;
        const bf16x8 v0 = *(const bf16x8*)&W1cG[j * 32 + gh * 16];
        const bf16x8 v1 = *(const bf16x8*)&W1cG[j * 32 + gh * 16 + 8];
        const int c3 = (j >> 3) & 3;
        const int s0 = ((gh * 2 + 0) + 3 * c3) & 7;
        const int s1 = ((gh * 2 + 1) + 3 * c3) & 7;
        *(bf16x8*)&sBg[j][s0 * 8] = v0;
        *(bf16x8*)&sBg[j][s1 * 8] = v1;
    }
    {   // k32..63 = SA rows (bf16 copy, transposed scatter)
        const int j = t & 255, kh = t >> 8;
        #pragma unroll
        for (int kk = 0; kk < 16; ++kk) {
            const int k = 32 + kh * 16 + kk;
            const short v = SA[(size_t)(node0 + (k - 32)) * 256 + j];
            const int slot = ((k >> 3) + 3 * ((j >> 3) & 3)) & 7;
            sBg[j][slot * 8 + (k & 7)] = v;
        }
    }
    if (t < 64) {
        short* d = &sW1da[0][0];
        *(bf16x8*)&d[t * 8] = *(const bf16x8*)&W1daP[t * 8];
    }
    if (t < 32) *(bf16x8*)&sW2p[t * 8] = *(const bf16x8*)&W2pP[t * 8];
    if (t < 96) sPosS[t / 3][t % 3] = pos[node0 * 3 + t];
    __syncthreads();

    bf16x8 w2efr[16];
    #pragma unroll
    for (int kk = 0; kk < 16; ++kk)
        w2efr[kk] = *(const bf16x8*)&W2eimg[(size_t)(kk * 64 + lane) * 8];
    float b1v[8];
    short w1dv[8], w1av[8];
    #pragma unroll
    for (int cb = 0; cb < 8; ++cb) {
        b1v[cb]  = b1[cb * 32 + l];
        w1dv[cb] = sW1da[0][cb * 32 + l];
        w1av[cb] = sW1da[1][cb * 32 + l];
    }
    const float b2e = b2[321 + l];
    const float b2p = b2[320];
    int bslot[4];
    #pragma unroll
    for (int ks = 0; ks < 4; ++ks)
        bslot[ks] = ((ks * 2 + half) + 3 * ((l >> 3) & 3)) & 7;

    for (int ni = 0; ni < 2; ++ni) {
        const int n = nbase + wave + ni * 8;
        const int rrc = (l < 31) ? l : 30;
        const int src = rrc + (rrc >= n ? 1 : 0);
        const float ax = sPosS[n][0],  ay = sPosS[n][1],  az = sPosS[n][2];
        const float bx = sPosS[src][0], by = sPosS[src][1], bz = sPosS[src][2];
        const float rx = ax - bx, ry = ay - by, rz = az - bz;
        const float av = ax * bx + ay * by + az * bz;
        const float dd = sqrtf(fmaxf(rx * rx + ry * ry + rz * rz, 1e-6f));
        const float inv = 1.f / (1.f + dd);
        const float rnx = rx * inv, rny = ry * inv, rnz = rz * inv;

        const short* ebase = ebuf + ((size_t)((mol * 32 + n) * 31 + l)) * 32;
        const bf16x8 fr0 = *(const bf16x8*)(ebase + half * 8);
        const bf16x8 fr1 = *(const bf16x8*)(ebase + 16 + half * 8);
        bf16x8 fr2 = {}, fr3, fr4;
        if (half == 0) { fr2[0] = bfc(dd); fr2[1] = bfc(av); }
        #pragma unroll
        for (int jj = 0; jj < 8; ++jj) {
            fr3[jj] = (half * 8 + jj == src)      ? ONEBF : (short)0;
            fr4[jj] = (16 + half * 8 + jj == src) ? ONEBF : (short)0;
        }

        f32x16 accC = {}, accP = {};
        float Hacc[8];

        const int g = l >> 3, jlow = l & 7;
        #pragma unroll
        for (int cb = 0; cb < 8; ++cb) {
            const float sbv = bf2f(SB[(size_t)(node0 + n) * 256 + cb * 32 + l]) + b1v[cb];
            f32x16 acc;
            #pragma unroll
            for (int r = 0; r < 16; ++r) acc[r] = sbv;
            {
                const short* brow = &sBg[cb * 32 + l][0];
                __builtin_amdgcn_s_setprio(1);
                acc = __builtin_amdgcn_mfma_f32_32x32x16_bf16(fr0, *(const bf16x8*)(brow + bslot[0]*8), acc, 0,0,0);
                acc = __builtin_amdgcn_mfma_f32_32x32x16_bf16(fr1, *(const bf16x8*)(brow + bslot[1]*8), acc, 0,0,0);
                acc = __builtin_amdgcn_mfma_f32_32x32x16_bf16(fr3, *(const bf16x8*)(brow + bslot[2]*8), acc, 0,0,0);
                acc = __builtin_amdgcn_mfma_f32_32x32x16_bf16(fr4, *(const bf16x8*)(brow + bslot[3]*8), acc, 0,0,0);
                bf16x8 frB2 = {};
                if (half == 0) { frB2[0] = w1dv[cb]; frB2[1] = w1av[cb]; }
                acc = __builtin_amdgcn_mfma_f32_32x32x16_bf16(fr2, frB2, acc, 0,0,0);
                __builtin_amdgcn_s_setprio(0);
            }
            float hs = 0.f;
            #pragma unroll
            for (int r = 0; r < 16; ++r) {
                const int e = (r & 3) + 8 * (r >> 2) + 4 * half;
                float h = silu_f(acc[r]);
                if (half == 1 && r == 15) h = 0.f;   // pad row 31
                hs += h;
                sHdn[wave][e][((g + (e >> 3)) & 3) * 8 + jlow] = bfc(h);
            }
            Hacc[cb] = hs;
            #pragma unroll
            for (int q = 0; q < 2; ++q) {
                const int g2 = q * 2 + half;
                const bf16x8 afr  = *(const bf16x8*)&sHdn[wave][l][((g2 + (l >> 3)) & 3) * 8];
                const bf16x8 wpfr = *(const bf16x8*)&sW2p[cb * 32 + q * 16 + half * 8];
                accC = __builtin_amdgcn_mfma_f32_32x32x16_bf16(afr, w2efr[cb * 2 + q], accC, 0,0,0);
                accP = __builtin_amdgcn_mfma_f32_32x32x16_bf16(afr, wpfr, accP, 0,0,0);
            }
        }
        // H (bf16 out)
        #pragma unroll
        for (int cb = 0; cb < 8; ++cb) {
            const float v = Hacc[cb] + __shfl_xor(Hacc[cb], 32, 64);
            if (lane < 32) Hbuf[(size_t)(node0 + n) * 256 + cb * 32 + lane] = bfc(v);
        }
        // p: accP cols all equal; lanes l==0 (both halves) scatter 16 rows each
        if (l == 0) {
            #pragma unroll
            for (int q4 = 0; q4 < 4; ++q4) {
                float4 pv = { accP[q4 * 4 + 0], accP[q4 * 4 + 1],
                              accP[q4 * 4 + 2], accP[q4 * 4 + 3] };
                *(float4*)&sP[wave][q4 * 8 + 4 * half] = pv;
            }
        }
        const float pown = sP[wave][l];
        const float pfull = (half == 0 && l < 31) ? (pown + b2p) : 0.f;
        float pd0 = rnx * pfull, pd1 = rny * pfull, pd2 = rnz * pfull;
        #pragma unroll
        for (int m = 1; m <= 32; m <<= 1) {
            pd0 += __shfl_xor(pd0, m, 64);
            pd1 += __shfl_xor(pd1, m, 64);
            pd2 += __shfl_xor(pd2, m, 64);
        }
        if (lane == 0) {
            pdelta[(size_t)(node0 + n) * 3 + 0] = pd0;
            pdelta[(size_t)(node0 + n) * 3 + 1] = pd1;
            pdelta[(size_t)(node0 + n) * 3 + 2] = pd2;
        }
        // e update (bf16 RMW)
        #pragma unroll
        for (int r = 0; r < 16; ++r) {
            const int e = (r & 3) + 8 * (r >> 2) + 4 * half;
            if (e < 31) {
                short* ep = ebuf + ((size_t)((mol * 32 + n) * 31 + e)) * 32 + l;
                *ep = bfc(bf2f(*ep) + accC[r] + b2e);
            }
        }
    }
}

// ---------------------------------------------------------------------------
// MFMA bond kernel (bf16 ebuf + bf16 U), staging from images.
// ---------------------------------------------------------------------------
__global__ __launch_bounds__(512) void bond_mfma(
    const short* __restrict__ U, const float* __restrict__ pos,
    const short* __restrict__ ebuf, const short* __restrict__ We1cG,
    const short* __restrict__ WdP, const short* __restrict__ We2img,
    const float* __restrict__ be1, const float* __restrict__ be2,
    float* __restrict__ outB)
{
    const int blk = blockIdx.x;
    const int mol = blk >> 1;
    const int nbase = (blk & 1) * 16;
    const int t = threadIdx.x;
    const int wave = t >> 6, lane = t & 63;
    const int l = lane & 31, half = lane >> 5;
    const int node0 = mol * 32;

    __shared__ __align__(16) short sBg2[128][72];
    __shared__ __align__(16) short sHdnB[8][32][40];
    __shared__ float sPosS[32][4];
    __shared__ __align__(16) short sWd[128];

    {   // k0..31 = We1c from image: one bf16x8 (16B) per thread
        const int j = t & 127, g = t >> 7;
        const bf16x8 v = *(const bf16x8*)&We1cG[j * 32 + g * 8];
        const int slot = (g + 3 * ((j >> 3) & 3)) & 7;
        *(bf16x8*)&sBg2[j][slot * 8] = v;
    }
    {   // k32..63 = U rows
        const int j = t & 127, kq = t >> 7;
        #pragma unroll
        for (int kk = 0; kk < 8; ++kk) {
            const int k = 32 + kq * 8 + kk;
            const short v = U[(size_t)(node0 + (k - 32)) * 128 + j];
            const int slot = ((k >> 3) + 3 * ((j >> 3) & 3)) & 7;
            sBg2[j][slot * 8 + (k & 7)] = v;
        }
    }
    if (t < 16) *(bf16x8*)&sWd[t * 8] = *(const bf16x8*)&WdP[t * 8];
    if (t < 96) sPosS[t / 3][t % 3] = pos[node0 * 3 + t];

    bf16x8 w2fr[8];
    #pragma unroll
    for (int kk = 0; kk < 8; ++kk)
        w2fr[kk] = *(const bf16x8*)&We2img[(size_t)(kk * 64 + lane) * 8];
    float be1v[4];
    #pragma unroll
    for (int cb = 0; cb < 4; ++cb) be1v[cb] = be1[cb * 32 + l];
    const float be2v = (l < 5) ? be2[l] : 0.f;
    int bslot[4];
    #pragma unroll
    for (int ks = 0; ks < 4; ++ks)
        bslot[ks] = ((ks * 2 + half) + 3 * ((l >> 3) & 3)) & 7;
    __syncthreads();

    for (int ni = 0; ni < 2; ++ni) {
        const int n = nbase + wave + ni * 8;
        const int rrc = (l < 31) ? l : 30;
        const int src = rrc + (rrc >= n ? 1 : 0);
        const float rx = sPosS[n][0] - sPosS[src][0];
        const float ry = sPosS[n][1] - sPosS[src][1];
        const float rz = sPosS[n][2] - sPosS[src][2];
        const float dd = sqrtf(fmaxf(rx * rx + ry * ry + rz * rz, 1e-6f));

        const short* ebase = ebuf + ((size_t)((mol * 32 + n) * 31 + l)) * 32;
        const bf16x8 fr0 = *(const bf16x8*)(ebase + half * 8);
        const bf16x8 fr1 = *(const bf16x8*)(ebase + 16 + half * 8);
        bf16x8 fr2 = {}, fr3, fr4;
        if (half == 0) fr2[0] = bfc(dd);
        #pragma unroll
        for (int jj = 0; jj < 8; ++jj) {
            fr3[jj] = (half * 8 + jj == src)      ? ONEBF : (short)0;
            fr4[jj] = (16 + half * 8 + jj == src) ? ONEBF : (short)0;
        }

        f32x16 accC = {};
        const int g = l >> 3, jlow = l & 7;
        #pragma unroll
        for (int cb = 0; cb < 4; ++cb) {
            const float uin = bf2f(U[(size_t)(node0 + n) * 128 + cb * 32 + l]) + be1v[cb];
            f32x16 acc;
            #pragma unroll
            for (int r = 0; r < 16; ++r) acc[r] = uin;
            {
                const short* brow = &sBg2[cb * 32 + l][0];
                acc = __builtin_amdgcn_mfma_f32_32x32x16_bf16(fr0, *(const bf16x8*)(brow + bslot[0]*8), acc, 0,0,0);
                acc = __builtin_amdgcn_mfma_f32_32x32x16_bf16(fr1, *(const bf16x8*)(brow + bslot[1]*8), acc, 0,0,0);
                acc = __builtin_amdgcn_mfma_f32_32x32x16_bf16(fr3, *(const bf16x8*)(brow + bslot[2]*8), acc, 0,0,0);
                acc = __builtin_amdgcn_mfma_f32_32x32x16_bf16(fr4, *(const bf16x8*)(brow + bslot[3]*8), acc, 0,0,0);
                bf16x8 frWd = {};
                if (half == 0) frWd[0] = sWd[cb * 32 + l];
                acc = __builtin_amdgcn_mfma_f32_32x32x16_bf16(fr2, frWd, acc, 0,0,0);
            }
            #pragma unroll
            for (int r = 0; r < 16; ++r) {
                const int e = (r & 3) + 8 * (r >> 2) + 4 * half;
                sHdnB[wave][e][((g + (e >> 3)) & 3) * 8 + jlow] = bfc(silu_f(acc[r]));
            }
            #pragma unroll
            for (int q = 0; q < 2; ++q) {
                const int g2 = q * 2 + half;
                const bf16x8 afr = *(const bf16x8*)&sHdnB[wave][l][((g2 + (l >> 3)) & 3) * 8];
                accC = __builtin_amdgcn_mfma_f32_32x32x16_bf16(afr, w2fr[cb * 2 + q], accC, 0,0,0);
            }
        }
        if (l < 5) {
            #pragma unroll
            for (int r = 0; r < 16; ++r) {
                const int e = (r & 3) + 8 * (r >> 2) + 4 * half;
                if (e < 31) {
                    const int s_ = e + (e >= n ? 1 : 0);
                    const int ge = (mol * 32 + s_) * 31 + (n - (n > s_ ? 1 : 0));
                    outB[(size_t)ge * 5 + l] = accC[r] + be2v;
                }
            }
        }
    }
}

// ---------------------------------------------------------------------------
__global__ __launch_bounds__(256) void pos_copy(const float* __restrict__ pos,
                                                float* __restrict__ out)
{
    const int i = blockIdx.x * 256 + threadIdx.x;
    out[i] = pos[i];
}

// ---------------------------------------------------------------------------
__global__ __launch_bounds__(256) void atoms_kernel(
    const short* __restrict__ tmp, const float* __restrict__ Wh2,
    const float* __restrict__ bh2, float* __restrict__ outA)
{
    const int gid = blockIdx.x * 256 + threadIdx.x;
    const int n = gid >> 4, o = gid & 15;
    float acc = bh2[o];
    #pragma unroll 8
    for (int k = 0; k < SDIM_; ++k) acc += bf2f(tmp[(size_t)n * SDIM_ + k]) * Wh2[k * NAF_ + o];
    outA[gid] = acc;
}

// ---------------------------------------------------------------------------
extern "C" void kernel_launch(void* const* d_in, const int* in_sizes, int n_in,
                              void* d_out, int out_size, void* d_ws, size_t ws_size,
                              hipStream_t stream) {
    const float* x   = (const float*)d_in[0];
    const float* z   = (const float*)d_in[1];
    const float* rot = (const float*)d_in[2];
    const float* ea  = (const float*)d_in[4];
    const float* Wam = (const float*)d_in[6];
    const float* bam = (const float*)d_in[7];
    const float* Wbm = (const float*)d_in[8];
    const float* bbm = (const float*)d_in[9];
    const float* gW1 = (const float*)d_in[10];
    const float* gb1 = (const float*)d_in[11];
    const float* gW2 = (const float*)d_in[12];
    const float* gb2 = (const float*)d_in[13];
    const float* Wh1 = (const float*)d_in[14];
    const float* bh1 = (const float*)d_in[15];
    const float* Wh2 = (const float*)d_in[16];
    const float* bh2 = (const float*)d_in[17];
    const float* We1 = (const float*)d_in[18];
    const float* be1 = (const float*)d_in[19];
    const float* We2 = (const float*)d_in[20];
    const float* be2 = (const float*)d_in[21];
    float* out = (float*)d_out;

    float* ws  = (float*)d_ws;
    float* s   = ws;                       // 8192*256 fp32
    float* pos = ws + 2097152;             // 8192*3
    short* e   = (short*)(ws + 2121728);   // 8192*31*32 bf16
    short* wb  = (short*)(ws + 6184960);   // weight images (1,175,424 shorts)
    short* sbf = (short*)(ws + 6772672);   // 8192*256 bf16 mirror of s
    short* SAh = (short*)(ws + 10248192);  // 8192*256 bf16
    short* SBh = (short*)(ws + 12345344);  // 8192*256 bf16
    short* Hh  = (short*)(ws + 14442496);  // 8192*256 bf16
    float* pd  = ws + 16539648;            // 8192*3
    short* tmph = SAh;                     // reuse after layers
    short* Uh   = Hh;                      // reuse after layers

    prep_weights<<<1024, 256, 0, stream>>>(gW1, gW2, Wh1, We1, We2, wb);
    node_init2<<<N_MOLS, 256, 0, stream>>>(x, z, rot, Wam, bam, s, sbf, pos);
    edge_init2<<<NN, 256, 0, stream>>>(ea, Wbm, bbm, e);

    for (int l = 0; l < LAYERS_; ++l) {
        const float* b1 = gb1 + l * 256;
        const float* b2 = gb2 + l * 353;
        gemm_dual2<<<dim3(8, 64), 256, 0, stream>>>(
            sbf, wb + OFF_T1 + (size_t)l * 131072, SAh, SBh);
        edge_mfma<<<2 * N_MOLS, 512, 0, stream>>>(
            SAh, SBh, pos, e,
            wb + OFF_W1CG + l * 8192, wb + OFF_W1DA + l * 512,
            wb + OFF_W2P + l * 256, wb + OFF_W2EI + l * 8192,
            b1, b2, Hh, pd);
        // s += (H @ W2s)/31 + b2[0:256]; also refresh sbf; fused pos += pd/31
        gemm_mfma<0,1,1,0,1><<<dim3(4, 64), 256, 0, stream>>>(
            Hh, wb + OFF_W2ST + (size_t)l * 65536, s, b2, 256, 256,
            1.f / 31.f, pos, pd, sbf);
    }

    gemm_mfma<1,0,0,1,0><<<dim3(4, 64), 256, 0, stream>>>(
        sbf, wb + OFF_WH1T, tmph, bh1, 256, 256, 1.f, nullptr, nullptr, nullptr);
    atoms_kernel<<<512, 256, 0, stream>>>(tmph, Wh2, bh2, out);

    gemm_mfma<0,0,0,1,0><<<dim3(2, 64), 256, 0, stream>>>(
        sbf, wb + OFF_WE1T, Uh, nullptr, 256, 128, 1.f, nullptr, nullptr, nullptr);
    bond_mfma<<<2 * N_MOLS, 512, 0, stream>>>(
        Uh, pos, e, wb + OFF_WE1CG, wb + OFF_WD, wb + OFF_WE2I,
        be1, be2, out + 131072);

    pos_copy<<<96, 256, 0, stream>>>(pos, out + 131072 + 1269760);
}

// Round 3
// 741.764 us; speedup vs baseline: 1.2034x; 1.0286x over previous
//
#include <hip/hip_runtime.h>
#include <hip/hip_bf16.h>
#include <cstdint>
#include <cstddef>

#define N_MOLS 256
#define NN     8192
#define SDIM_  256
#define NAF_   16
#define LAYERS_ 5

typedef __attribute__((ext_vector_type(8)))  short bf16x8;
typedef __attribute__((ext_vector_type(16))) float f32x16;

__device__ __forceinline__ float silu_f(float x) {
    return x / (1.f + __expf(-x));
}
__device__ __forceinline__ short bfc(float f) {
    __hip_bfloat16 h = __float2bfloat16(f);
    return __builtin_bit_cast(short, h);
}
__device__ __forceinline__ float bf2f(short h) {
    union { uint32_t u; float f; } v; v.u = ((uint32_t)(unsigned short)h) << 16; return v.f;
}
#define ONEBF ((short)0x3F80)

// ---------------------------------------------------------------------------
// weight image offsets (in shorts, within wb)
// ---------------------------------------------------------------------------
#define OFF_T1    0         // 5 * 512*256   : W1ab^T  [l][j2][k]
#define OFF_W2ST  655360    // 5 * 256*256   : W2s^T   [l][n][k]
#define OFF_WH1T  983040    // 256*256       : Wh1^T   [n][k]
#define OFF_WE1T  1048576   // 128*256       : We1^T   [n][k]
#define OFF_W1CG  1081344   // 5 * 256*32    : W1c slot groups [l][j][w]
#define OFF_W1DA  1122304   // 5 * 2*256    : W1 d/a rows
#define OFF_W2P   1124864   // 5 * 256       : W2 col 320
#define OFF_W2EI  1126144   // 5 * 8192      : sW2e fragment image
#define OFF_WE1CG 1167104   // 128*32        : We1c slot groups
#define OFF_WD    1171200   // 128           : We1 row 288
#define OFF_WE2I  1171328   // 8*64*8        : We2 fragment image
#define W_TOTAL   1175424

// ---------------------------------------------------------------------------
// one-shot weight conversion / transpose / swizzle into bf16 images
// ---------------------------------------------------------------------------
__global__ __launch_bounds__(256) void prep_weights(
    const float* __restrict__ gW1, const float* __restrict__ gW2,
    const float* __restrict__ Wh1, const float* __restrict__ We1,
    const float* __restrict__ We2, short* __restrict__ wb)
{
    for (int o = blockIdx.x * 256 + threadIdx.x; o < W_TOTAL; o += gridDim.x * 256) {
        float v;
        if (o < OFF_W2ST) {                       // T1 [l][j2<512][k<256]
            const int l = o >> 17, r = o & 131071;
            const int j2 = r >> 8, k = r & 255;
            v = gW1[(size_t)l * 139776 + (size_t)((j2 >> 8) * 256 + k) * 256 + (j2 & 255)];
        } else if (o < OFF_WH1T) {                // W2sT [l][n][k]
            const int q = o - OFF_W2ST;
            const int l = q >> 16, r = q & 65535;
            const int n = r >> 8, k = r & 255;
            v = gW2[(size_t)l * 90368 + (size_t)k * 353 + n];
        } else if (o < OFF_WE1T) {                // Wh1T [n][k]
            const int q = o - OFF_WH1T;
            v = Wh1[(size_t)(q & 255) * 256 + (q >> 8)];
        } else if (o < OFF_W1CG) {                // We1T [n][k]
            const int q = o - OFF_WE1T;
            v = We1[(size_t)(q & 255) * 128 + (q >> 8)];
        } else if (o < OFF_W1DA) {                // W1cG [l][j][w]: w = g*8+kk, k = 512+w
            const int q = o - OFF_W1CG;
            const int l = q >> 13, r = q & 8191;
            const int j = r >> 5, w = r & 31;
            v = gW1[(size_t)l * 139776 + (size_t)(512 + w) * 256 + j];
        } else if (o < OFF_W2P) {                 // W1da [l][d][j]
            const int q = o - OFF_W1DA;
            const int l = q >> 9, r = q & 511;
            v = gW1[(size_t)l * 139776 + (size_t)(544 + (r >> 8)) * 256 + (r & 255)];
        } else if (o < OFF_W2EI) {                // W2p [l][j]
            const int q = o - OFF_W2P;
            v = gW2[(size_t)(q >> 8) * 90368 + (size_t)(q & 255) * 353 + 320];
        } else if (o < OFF_WE1CG) {               // W2e fragment image [l][idx]
            const int q = o - OFF_W2EI;
            const int l = q >> 13, r = q & 8191;
            const int kk = r >> 9, lanei = (r >> 3) & 63, jj = r & 7;
            const int j = kk * 16 + (lanei >> 5) * 8 + jj;
            v = gW2[(size_t)l * 90368 + (size_t)j * 353 + 321 + (lanei & 31)];
        } else if (o < OFF_WD) {                  // We1cG [j][w]: k = 256+w
            const int q = o - OFF_WE1CG;
            v = We1[(size_t)(256 + (q & 31)) * 128 + (q >> 5)];
        } else if (o < OFF_WE2I) {                // Wd [j]
            v = We1[288 * 128 + (o - OFF_WD)];
        } else {                                  // We2 fragment image
            const int q = o - OFF_WE2I;
            const int kk = q >> 9, lanei = (q >> 3) & 63, jj = q & 7;
            const int c = lanei & 31;
            v = (c < 5) ? We2[(size_t)(kk * 16 + (lanei >> 5) * 8 + jj) * 5 + c] : 0.f;
        }
        wb[o] = bfc(v);
    }
}

// ---------------------------------------------------------------------------
// node init, 1 block per molecule: h = [x|z]@Wam+bam; s, sbf, pos
// ---------------------------------------------------------------------------
__global__ __launch_bounds__(256) void node_init2(
    const float* __restrict__ x, const float* __restrict__ z,
    const float* __restrict__ rot, const float* __restrict__ Wam,
    const float* __restrict__ bam, float* __restrict__ s,
    short* __restrict__ sbf, float* __restrict__ pos)
{
    const int mol = blockIdx.x, t = threadIdx.x;
    __shared__ __align__(16) float xz[32][80];
    __shared__ float praw[32][3];
    for (int idx = t; idx < 32 * 80; idx += 256) {
        const int i = idx / 80, k = idx % 80;
        xz[i][k] = (k < 16) ? x[(size_t)(mol * 32 + i) * 16 + k]
                            : z[(size_t)(mol * 32 + i) * 64 + (k - 16)];
    }
    __syncthreads();
    float acc[32];
    #pragma unroll
    for (int i = 0; i < 32; ++i) acc[i] = 0.f;
    for (int k0 = 0; k0 < 80; k0 += 4) {
        const float w0 = Wam[(k0 + 0) * 259 + t];
        const float w1 = Wam[(k0 + 1) * 259 + t];
        const float w2 = Wam[(k0 + 2) * 259 + t];
        const float w3 = Wam[(k0 + 3) * 259 + t];
        #pragma unroll
        for (int i = 0; i < 32; ++i) {
            const float4 xv = *(const float4*)&xz[i][k0];
            acc[i] += xv.x * w0 + xv.y * w1 + xv.z * w2 + xv.w * w3;
        }
    }
    const float bv = bam[t];
    #pragma unroll
    for (int i = 0; i < 32; ++i) {
        const float v = acc[i] + bv;
        s[(size_t)(mol * 32 + i) * 256 + t] = v;
        sbf[(size_t)(mol * 32 + i) * 256 + t] = bfc(v);
    }
    if (t < 96) {
        const int i = t / 3, c = t % 3;
        float a2 = bam[256 + c];
        for (int k = 0; k < 80; ++k) a2 += xz[i][k] * Wam[k * 259 + 256 + c];
        praw[i][c] = a2;
    }
    __syncthreads();
    if (t < 96) {
        const int i = t / 3, c = t % 3;
        float p = 0.f;
        for (int jj = 0; jj < 3; ++jj) p += rot[mol * 9 + c * 3 + jj] * praw[i][jj];
        pos[(size_t)(mol * 32 + i) * 3 + c] = p;
    }
}

// ---------------------------------------------------------------------------
// edge feature init (bf16 out), tgt-major: e[((mol*32+n)*31+rr)*32+c]
// ---------------------------------------------------------------------------
__global__ __launch_bounds__(256) void edge_init2(
    const float* __restrict__ ea, const float* __restrict__ Wbm,
    const float* __restrict__ bbm, short* __restrict__ ebuf)
{
    const int tile = blockIdx.x;
    const int mol = tile >> 5, n = tile & 31;
    const int t = threadIdx.x;
    for (int i = t; i < 31 * 32; i += 256) {
        const int rr = i >> 5, c = i & 31;
        const int s_ = rr + (rr >= n ? 1 : 0);
        const int ge = (mol * 32 + s_) * 31 + (n - (n > s_ ? 1 : 0));
        float acc = bbm[c];
        #pragma unroll
        for (int k = 0; k < 5; ++k) acc += ea[(size_t)ge * 5 + k] * Wbm[k * 32 + c];
        ebuf[(size_t)tile * 31 * 32 + i] = bfc(acc);
    }
}

// ---------------------------------------------------------------------------
// bf16 MFMA GEMM, A bf16 [m][k], B bf16 pre-transposed [n][k].
// C = act(alpha*(A@B)+bias); OUTBF: C written as bf16.
// ---------------------------------------------------------------------------
template<int ACT, int OUTBF>
__global__ __launch_bounds__(256) void gemm_mfma(
    const short* __restrict__ A, const short* __restrict__ BT,
    void* __restrict__ Cv, const float* __restrict__ bias,
    int K, int N, float alpha)
{
    const int n0 = blockIdx.x * 64, m0 = blockIdx.y * 128;
    const int t = threadIdx.x;
    const int wave = t >> 6, lane = t & 63;
    const int l = lane & 31, half = lane >> 5;
    const int wm = wave & 1, wn = wave >> 1;
    __shared__ __align__(16) short sA[128][40];
    __shared__ __align__(16) short sBt[64][40];
    f32x16 acc0 = {}, acc1 = {};
    const int mA = t >> 1, koA = (t & 1) * 16;
    const int nB = t & 63, kqB = (t >> 6) * 8;
    for (int k0 = 0; k0 < K; k0 += 32) {
        {
            const short* ap = A + (size_t)(m0 + mA) * K + k0 + koA;
            *(bf16x8*)&sA[mA][koA]     = *(const bf16x8*)(ap);
            *(bf16x8*)&sA[mA][koA + 8] = *(const bf16x8*)(ap + 8);
        }
        {
            const short* bp = BT + (size_t)(n0 + nB) * K + k0 + kqB;
            *(bf16x8*)&sBt[nB][kqB] = *(const bf16x8*)bp;
        }
        __syncthreads();
        #pragma unroll
        for (int ks = 0; ks < 2; ++ks) {
            const bf16x8 bfrag = *(const bf16x8*)&sBt[wn * 32 + l][ks * 16 + half * 8];
            const bf16x8 afr0  = *(const bf16x8*)&sA[wm * 64 + l][ks * 16 + half * 8];
            const bf16x8 afr1  = *(const bf16x8*)&sA[wm * 64 + 32 + l][ks * 16 + half * 8];
            acc0 = __builtin_amdgcn_mfma_f32_32x32x16_bf16(afr0, bfrag, acc0, 0,0,0);
            acc1 = __builtin_amdgcn_mfma_f32_32x32x16_bf16(afr1, bfrag, acc1, 0,0,0);
        }
        __syncthreads();
    }
    const int n = n0 + wn * 32 + l;
    const float bv = bias ? bias[n] : 0.f;
    #pragma unroll
    for (int r = 0; r < 16; ++r) {
        const int row = (r & 3) + 8 * (r >> 2) + 4 * half;
        #pragma unroll
        for (int h = 0; h < 2; ++h) {
            const int m = m0 + wm * 64 + h * 32 + row;
            float v = alpha * (h ? acc1[r] : acc0[r]) + bv;
            if (ACT) v = silu_f(v);
            if (OUTBF) ((short*)Cv)[(size_t)m * N + n] = bfc(v);
            else       ((float*)Cv)[(size_t)m * N + n] = v;
        }
    }
}

// ---------------------------------------------------------------------------
// Dual GEMM: SA = sbf@W1a, SB = sbf@W1b (bf16 out), B from T1 images.
// ---------------------------------------------------------------------------
__global__ __launch_bounds__(256) void gemm_dual2(
    const short* __restrict__ A, const short* __restrict__ T1l,
    short* __restrict__ C0, short* __restrict__ C1)
{
    const int K = 256, N = 256;
    const int sel = blockIdx.x >> 2;
    short* C = sel ? C1 : C0;
    const int n0 = (blockIdx.x & 3) * 64, m0 = blockIdx.y * 128;
    const int bRow0 = sel * 256 + n0;
    const int t = threadIdx.x;
    const int wave = t >> 6, lane = t & 63;
    const int l = lane & 31, half = lane >> 5;
    const int wm = wave & 1, wn = wave >> 1;
    __shared__ __align__(16) short sA[128][40];
    __shared__ __align__(16) short sBt[64][40];
    f32x16 acc0 = {}, acc1 = {};
    const int mA = t >> 1, koA = (t & 1) * 16;
    const int nB = t & 63, kqB = (t >> 6) * 8;
    for (int k0 = 0; k0 < K; k0 += 32) {
        {
            const short* ap = A + (size_t)(m0 + mA) * K + k0 + koA;
            *(bf16x8*)&sA[mA][koA]     = *(const bf16x8*)(ap);
            *(bf16x8*)&sA[mA][koA + 8] = *(const bf16x8*)(ap + 8);
        }
        {
            const short* bp = T1l + (size_t)(bRow0 + nB) * K + k0 + kqB;
            *(bf16x8*)&sBt[nB][kqB] = *(const bf16x8*)bp;
        }
        __syncthreads();
        #pragma unroll
        for (int ks = 0; ks < 2; ++ks) {
            const bf16x8 bfrag = *(const bf16x8*)&sBt[wn * 32 + l][ks * 16 + half * 8];
            const bf16x8 afr0  = *(const bf16x8*)&sA[wm * 64 + l][ks * 16 + half * 8];
            const bf16x8 afr1  = *(const bf16x8*)&sA[wm * 64 + 32 + l][ks * 16 + half * 8];
            acc0 = __builtin_amdgcn_mfma_f32_32x32x16_bf16(afr0, bfrag, acc0, 0,0,0);
            acc1 = __builtin_amdgcn_mfma_f32_32x32x16_bf16(afr1, bfrag, acc1, 0,0,0);
        }
        __syncthreads();
    }
    const int n = n0 + wn * 32 + l;
    #pragma unroll
    for (int r = 0; r < 16; ++r) {
        const int row = (r & 3) + 8 * (r >> 2) + 4 * half;
        C[(size_t)(m0 + wm * 64 + row) * N + n]      = bfc(acc0[r]);
        C[(size_t)(m0 + wm * 64 + 32 + row) * N + n] = bfc(acc1[r]);
    }
}

// ---------------------------------------------------------------------------
// MFMA edge kernel + fused s-update epilogue. Grid 512 (2/mol), 512 thr.
// Epilogue: s[n] += H[n]@W2s/31 + b2[0:256]; sbf refresh; posOut = posIn+pd/31.
// ---------------------------------------------------------------------------
__global__ __launch_bounds__(512) void edge_mfma(
    const short* __restrict__ SA, const short* __restrict__ SB,
    const float* __restrict__ posIn, float* __restrict__ posOut,
    short* __restrict__ ebuf,
    const short* __restrict__ W1cG, const short* __restrict__ W1daP,
    const short* __restrict__ W2pP, const short* __restrict__ W2eimg,
    const short* __restrict__ W2sT,
    const float* __restrict__ b1, const float* __restrict__ b2,
    float* __restrict__ s, short* __restrict__ sbf)
{
    const int blk = blockIdx.x;
    const int mol = blk >> 1;
    const int nbase = (blk & 1) * 16;
    const int t = threadIdx.x;
    const int wave = t >> 6, lane = t & 63;
    const int l = lane & 31, half = lane >> 5;
    const int node0 = mol * 32;

    __shared__ __align__(16) short sBg[256][72];    // 36 KB
    __shared__ __align__(16) short sHdn[8][32][40]; // 20 KB
    __shared__ __align__(16) short sHrows[32][264]; // 16.9 KB (rows 16..31 zero)
    __shared__ float sPosS[32][4];
    __shared__ __align__(16) short sW1da[2][256];
    __shared__ __align__(16) short sW2p[256];
    __shared__ float sP[8][32];
    __shared__ float sPd[16][4];

    {   // k0..31 = W1c from pre-swizzled image: 2 x bf16x8 (16B) per thread
        const int j = t & 255, gh = t >> 8;
        const bf16x8 v0 = *(const bf16x8*)&W1cG[j * 32 + gh * 16];
        const bf16x8 v1 = *(const bf16x8*)&W1cG[j * 32 + gh * 16 + 8];
        const int c3 = (j >> 3) & 3;
        const int s0 = ((gh * 2 + 0) + 3 * c3) & 7;
        const int s1 = ((gh * 2 + 1) + 3 * c3) & 7;
        *(bf16x8*)&sBg[j][s0 * 8] = v0;
        *(bf16x8*)&sBg[j][s1 * 8] = v1;
    }
    {   // k32..63 = SA rows (bf16 copy, transposed scatter)
        const int j = t & 255, kh = t >> 8;
        #pragma unroll
        for (int kk = 0; kk < 16; ++kk) {
            const int k = 32 + kh * 16 + kk;
            const short v = SA[(size_t)(node0 + (k - 32)) * 256 + j];
            const int slot = ((k >> 3) + 3 * ((j >> 3) & 3)) & 7;
            sBg[j][slot * 8 + (k & 7)] = v;
        }
    }
    // zero pad rows 16..31 of H-tile (A-operand rows for the fused GEMM)
    for (int i = t; i < 16 * 264; i += 512) (&sHrows[16][0])[i] = 0;
    if (t < 64) {
        short* d = &sW1da[0][0];
        *(bf16x8*)&d[t * 8] = *(const bf16x8*)&W1daP[t * 8];
    }
    if (t < 32) *(bf16x8*)&sW2p[t * 8] = *(const bf16x8*)&W2pP[t * 8];
    if (t < 96) sPosS[t / 3][t % 3] = posIn[node0 * 3 + t];
    __syncthreads();

    bf16x8 w2efr[16];
    #pragma unroll
    for (int kk = 0; kk < 16; ++kk)
        w2efr[kk] = *(const bf16x8*)&W2eimg[(size_t)(kk * 64 + lane) * 8];
    float b1v[8];
    short w1dv[8], w1av[8];
    #pragma unroll
    for (int cb = 0; cb < 8; ++cb) {
        b1v[cb]  = b1[cb * 32 + l];
        w1dv[cb] = sW1da[0][cb * 32 + l];
        w1av[cb] = sW1da[1][cb * 32 + l];
    }
    const float b2e = b2[321 + l];
    const float b2p = b2[320];
    int bslot[4];
    #pragma unroll
    for (int ks = 0; ks < 4; ++ks)
        bslot[ks] = ((ks * 2 + half) + 3 * ((l >> 3) & 3)) & 7;

    for (int ni = 0; ni < 2; ++ni) {
        const int n = nbase + wave + ni * 8;
        const int nloc = wave + ni * 8;
        const int rrc = (l < 31) ? l : 30;
        const int src = rrc + (rrc >= n ? 1 : 0);
        const float ax = sPosS[n][0],  ay = sPosS[n][1],  az = sPosS[n][2];
        const float bx = sPosS[src][0], by = sPosS[src][1], bz = sPosS[src][2];
        const float rx = ax - bx, ry = ay - by, rz = az - bz;
        const float av = ax * bx + ay * by + az * bz;
        const float dd = sqrtf(fmaxf(rx * rx + ry * ry + rz * rz, 1e-6f));
        const float inv = 1.f / (1.f + dd);
        const float rnx = rx * inv, rny = ry * inv, rnz = rz * inv;

        const short* ebase = ebuf + ((size_t)((mol * 32 + n) * 31 + l)) * 32;
        const bf16x8 fr0 = *(const bf16x8*)(ebase + half * 8);
        const bf16x8 fr1 = *(const bf16x8*)(ebase + 16 + half * 8);
        bf16x8 fr2 = {}, fr3, fr4;
        if (half == 0) { fr2[0] = bfc(dd); fr2[1] = bfc(av); }
        #pragma unroll
        for (int jj = 0; jj < 8; ++jj) {
            fr3[jj] = (half * 8 + jj == src)      ? ONEBF : (short)0;
            fr4[jj] = (16 + half * 8 + jj == src) ? ONEBF : (short)0;
        }

        f32x16 accC = {}, accP = {};
        float Hacc[8];

        const int g = l >> 3, jlow = l & 7;
        #pragma unroll
        for (int cb = 0; cb < 8; ++cb) {
            const float sbv = bf2f(SB[(size_t)(node0 + n) * 256 + cb * 32 + l]) + b1v[cb];
            f32x16 acc;
            #pragma unroll
            for (int r = 0; r < 16; ++r) acc[r] = sbv;
            {
                const short* brow = &sBg[cb * 32 + l][0];
                __builtin_amdgcn_s_setprio(1);
                acc = __builtin_amdgcn_mfma_f32_32x32x16_bf16(fr0, *(const bf16x8*)(brow + bslot[0]*8), acc, 0,0,0);
                acc = __builtin_amdgcn_mfma_f32_32x32x16_bf16(fr1, *(const bf16x8*)(brow + bslot[1]*8), acc, 0,0,0);
                acc = __builtin_amdgcn_mfma_f32_32x32x16_bf16(fr3, *(const bf16x8*)(brow + bslot[2]*8), acc, 0,0,0);
                acc = __builtin_amdgcn_mfma_f32_32x32x16_bf16(fr4, *(const bf16x8*)(brow + bslot[3]*8), acc, 0,0,0);
                bf16x8 frB2 = {};
                if (half == 0) { frB2[0] = w1dv[cb]; frB2[1] = w1av[cb]; }
                acc = __builtin_amdgcn_mfma_f32_32x32x16_bf16(fr2, frB2, acc, 0,0,0);
                __builtin_amdgcn_s_setprio(0);
            }
            float hs = 0.f;
            #pragma unroll
            for (int r = 0; r < 16; ++r) {
                const int e = (r & 3) + 8 * (r >> 2) + 4 * half;
                float h = silu_f(acc[r]);
                if (half == 1 && r == 15) h = 0.f;   // pad row 31
                hs += h;
                sHdn[wave][e][((g + (e >> 3)) & 3) * 8 + jlow] = bfc(h);
            }
            Hacc[cb] = hs;
            #pragma unroll
            for (int q = 0; q < 2; ++q) {
                const int g2 = q * 2 + half;
                const bf16x8 afr  = *(const bf16x8*)&sHdn[wave][l][((g2 + (l >> 3)) & 3) * 8];
                const bf16x8 wpfr = *(const bf16x8*)&sW2p[cb * 32 + q * 16 + half * 8];
                accC = __builtin_amdgcn_mfma_f32_32x32x16_bf16(afr, w2efr[cb * 2 + q], accC, 0,0,0);
                accP = __builtin_amdgcn_mfma_f32_32x32x16_bf16(afr, wpfr, accP, 0,0,0);
            }
        }
        // H row into LDS tile (bf16)
        #pragma unroll
        for (int cb = 0; cb < 8; ++cb) {
            const float v = Hacc[cb] + __shfl_xor(Hacc[cb], 32, 64);
            if (lane < 32) sHrows[nloc][cb * 32 + lane] = bfc(v);
        }
        // p: accP cols all equal; lanes l==0 (both halves) scatter 16 rows each
        if (l == 0) {
            #pragma unroll
            for (int q4 = 0; q4 < 4; ++q4) {
                float4 pv = { accP[q4 * 4 + 0], accP[q4 * 4 + 1],
                              accP[q4 * 4 + 2], accP[q4 * 4 + 3] };
                *(float4*)&sP[wave][q4 * 8 + 4 * half] = pv;
            }
        }
        const float pown = sP[wave][l];
        const float pfull = (half == 0 && l < 31) ? (pown + b2p) : 0.f;
        float pd0 = rnx * pfull, pd1 = rny * pfull, pd2 = rnz * pfull;
        #pragma unroll
        for (int m = 1; m <= 32; m <<= 1) {
            pd0 += __shfl_xor(pd0, m, 64);
            pd1 += __shfl_xor(pd1, m, 64);
            pd2 += __shfl_xor(pd2, m, 64);
        }
        if (lane == 0) {
            sPd[nloc][0] = pd0;
            sPd[nloc][1] = pd1;
            sPd[nloc][2] = pd2;
        }
        // e update (bf16 RMW)
        #pragma unroll
        for (int r = 0; r < 16; ++r) {
            const int e = (r & 3) + 8 * (r >> 2) + 4 * half;
            if (e < 31) {
                short* ep = ebuf + ((size_t)((mol * 32 + n) * 31 + e)) * 32 + l;
                *ep = bfc(bf2f(*ep) + accC[r] + b2e);
            }
        }
    }

    __syncthreads();  // H-tile + sPd complete

    // fused s-update: D = H(16x256, padded to 32) @ W2s (wave -> 32 out-cols)
    {
        const int n0w = wave * 32;
        f32x16 accS = {};
        #pragma unroll
        for (int k0 = 0; k0 < 256; k0 += 16) {
            const bf16x8 afr = *(const bf16x8*)&sHrows[l][k0 + half * 8];
            const bf16x8 bfr = *(const bf16x8*)&W2sT[(size_t)(n0w + l) * 256 + k0 + half * 8];
            accS = __builtin_amdgcn_mfma_f32_32x32x16_bf16(afr, bfr, accS, 0,0,0);
        }
        const float bv = b2[n0w + l];
        #pragma unroll
        for (int r = 0; r < 8; ++r) {
            const int row = (r & 3) + 8 * (r >> 2) + 4 * half;  // 0..15
            const int node = node0 + nbase + row;
            float* sp = s + (size_t)node * 256 + n0w + l;
            const float nv = *sp + accS[r] * (1.f / 31.f) + bv;
            *sp = nv;
            sbf[(size_t)node * 256 + n0w + l] = bfc(nv);
        }
    }
    // pos update
    if (t < 48) {
        const int nl = t / 3, c = t % 3;
        const int node = node0 + nbase + nl;
        posOut[(size_t)node * 3 + c] = posIn[(size_t)node * 3 + c] + sPd[nl][c] * (1.f / 31.f);
    }
}

// ---------------------------------------------------------------------------
// MFMA bond kernel (bf16 ebuf + bf16 U), staging from images.
// ---------------------------------------------------------------------------
__global__ __launch_bounds__(512) void bond_mfma(
    const short* __restrict__ U, const float* __restrict__ pos,
    const short* __restrict__ ebuf, const short* __restrict__ We1cG,
    const short* __restrict__ WdP, const short* __restrict__ We2img,
    const float* __restrict__ be1, const float* __restrict__ be2,
    float* __restrict__ outB)
{
    const int blk = blockIdx.x;
    const int mol = blk >> 1;
    const int nbase = (blk & 1) * 16;
    const int t = threadIdx.x;
    const int wave = t >> 6, lane = t & 63;
    const int l = lane & 31, half = lane >> 5;
    const int node0 = mol * 32;

    __shared__ __align__(16) short sBg2[128][72];
    __shared__ __align__(16) short sHdnB[8][32][40];
    __shared__ float sPosS[32][4];
    __shared__ __align__(16) short sWd[128];

    {   // k0..31 = We1c from image: one bf16x8 (16B) per thread
        const int j = t & 127, g = t >> 7;
        const bf16x8 v = *(const bf16x8*)&We1cG[j * 32 + g * 8];
        const int slot = (g + 3 * ((j >> 3) & 3)) & 7;
        *(bf16x8*)&sBg2[j][slot * 8] = v;
    }
    {   // k32..63 = U rows
        const int j = t & 127, kq = t >> 7;
        #pragma unroll
        for (int kk = 0; kk < 8; ++kk) {
            const int k = 32 + kq * 8 + kk;
            const short v = U[(size_t)(node0 + (k - 32)) * 128 + j];
            const int slot = ((k >> 3) + 3 * ((j >> 3) & 3)) & 7;
            sBg2[j][slot * 8 + (k & 7)] = v;
        }
    }
    if (t < 16) *(bf16x8*)&sWd[t * 8] = *(const bf16x8*)&WdP[t * 8];
    if (t < 96) sPosS[t / 3][t % 3] = pos[node0 * 3 + t];

    bf16x8 w2fr[8];
    #pragma unroll
    for (int kk = 0; kk < 8; ++kk)
        w2fr[kk] = *(const bf16x8*)&We2img[(size_t)(kk * 64 + lane) * 8];
    float be1v[4];
    #pragma unroll
    for (int cb = 0; cb < 4; ++cb) be1v[cb] = be1[cb * 32 + l];
    const float be2v = (l < 5) ? be2[l] : 0.f;
    int bslot[4];
    #pragma unroll
    for (int ks = 0; ks < 4; ++ks)
        bslot[ks] = ((ks * 2 + half) + 3 * ((l >> 3) & 3)) & 7;
    __syncthreads();

    for (int ni = 0; ni < 2; ++ni) {
        const int n = nbase + wave + ni * 8;
        const int rrc = (l < 31) ? l : 30;
        const int src = rrc + (rrc >= n ? 1 : 0);
        const float rx = sPosS[n][0] - sPosS[src][0];
        const float ry = sPosS[n][1] - sPosS[src][1];
        const float rz = sPosS[n][2] - sPosS[src][2];
        const float dd = sqrtf(fmaxf(rx * rx + ry * ry + rz * rz, 1e-6f));

        const short* ebase = ebuf + ((size_t)((mol * 32 + n) * 31 + l)) * 32;
        const bf16x8 fr0 = *(const bf16x8*)(ebase + half * 8);
        const bf16x8 fr1 = *(const bf16x8*)(ebase + 16 + half * 8);
        bf16x8 fr2 = {}, fr3, fr4;
        if (half == 0) fr2[0] = bfc(dd);
        #pragma unroll
        for (int jj = 0; jj < 8; ++jj) {
            fr3[jj] = (half * 8 + jj == src)      ? ONEBF : (short)0;
            fr4[jj] = (16 + half * 8 + jj == src) ? ONEBF : (short)0;
        }

        f32x16 accC = {};
        const int g = l >> 3, jlow = l & 7;
        #pragma unroll
        for (int cb = 0; cb < 4; ++cb) {
            const float uin = bf2f(U[(size_t)(node0 + n) * 128 + cb * 32 + l]) + be1v[cb];
            f32x16 acc;
            #pragma unroll
            for (int r = 0; r < 16; ++r) acc[r] = uin;
            {
                const short* brow = &sBg2[cb * 32 + l][0];
                acc = __builtin_amdgcn_mfma_f32_32x32x16_bf16(fr0, *(const bf16x8*)(brow + bslot[0]*8), acc, 0,0,0);
                acc = __builtin_amdgcn_mfma_f32_32x32x16_bf16(fr1, *(const bf16x8*)(brow + bslot[1]*8), acc, 0,0,0);
                acc = __builtin_amdgcn_mfma_f32_32x32x16_bf16(fr3, *(const bf16x8*)(brow + bslot[2]*8), acc, 0,0,0);
                acc = __builtin_amdgcn_mfma_f32_32x32x16_bf16(fr4, *(const bf16x8*)(brow + bslot[3]*8), acc, 0,0,0);
                bf16x8 frWd = {};
                if (half == 0) frWd[0] = sWd[cb * 32 + l];
                acc = __builtin_amdgcn_mfma_f32_32x32x16_bf16(fr2, frWd, acc, 0,0,0);
            }
            #pragma unroll
            for (int r = 0; r < 16; ++r) {
                const int e = (r & 3) + 8 * (r >> 2) + 4 * half;
                sHdnB[wave][e][((g + (e >> 3)) & 3) * 8 + jlow] = bfc(silu_f(acc[r]));
            }
            #pragma unroll
            for (int q = 0; q < 2; ++q) {
                const int g2 = q * 2 + half;
                const bf16x8 afr = *(const bf16x8*)&sHdnB[wave][l][((g2 + (l >> 3)) & 3) * 8];
                accC = __builtin_amdgcn_mfma_f32_32x32x16_bf16(afr, w2fr[cb * 2 + q], accC, 0,0,0);
            }
        }
        if (l < 5) {
            #pragma unroll
            for (int r = 0; r < 16; ++r) {
                const int e = (r & 3) + 8 * (r >> 2) + 4 * half;
                if (e < 31) {
                    const int s_ = e + (e >= n ? 1 : 0);
                    const int ge = (mol * 32 + s_) * 31 + (n - (n > s_ ? 1 : 0));
                    outB[(size_t)ge * 5 + l] = accC[r] + be2v;
                }
            }
        }
    }
}

// ---------------------------------------------------------------------------
__global__ __launch_bounds__(256) void pos_copy(const float* __restrict__ pos,
                                                float* __restrict__ out)
{
    const int i = blockIdx.x * 256 + threadIdx.x;
    out[i] = pos[i];
}

// ---------------------------------------------------------------------------
__global__ __launch_bounds__(256) void atoms_kernel(
    const short* __restrict__ tmp, const float* __restrict__ Wh2,
    const float* __restrict__ bh2, float* __restrict__ outA)
{
    const int gid = blockIdx.x * 256 + threadIdx.x;
    const int n = gid >> 4, o = gid & 15;
    float acc = bh2[o];
    #pragma unroll 8
    for (int k = 0; k < SDIM_; ++k) acc += bf2f(tmp[(size_t)n * SDIM_ + k]) * Wh2[k * NAF_ + o];
    outA[gid] = acc;
}

// ---------------------------------------------------------------------------
extern "C" void kernel_launch(void* const* d_in, const int* in_sizes, int n_in,
                              void* d_out, int out_size, void* d_ws, size_t ws_size,
                              hipStream_t stream) {
    const float* x   = (const float*)d_in[0];
    const float* z   = (const float*)d_in[1];
    const float* rot = (const float*)d_in[2];
    const float* ea  = (const float*)d_in[4];
    const float* Wam = (const float*)d_in[6];
    const float* bam = (const float*)d_in[7];
    const float* Wbm = (const float*)d_in[8];
    const float* bbm = (const float*)d_in[9];
    const float* gW1 = (const float*)d_in[10];
    const float* gb1 = (const float*)d_in[11];
    const float* gW2 = (const float*)d_in[12];
    const float* gb2 = (const float*)d_in[13];
    const float* Wh1 = (const float*)d_in[14];
    const float* bh1 = (const float*)d_in[15];
    const float* Wh2 = (const float*)d_in[16];
    const float* bh2 = (const float*)d_in[17];
    const float* We1 = (const float*)d_in[18];
    const float* be1 = (const float*)d_in[19];
    const float* We2 = (const float*)d_in[20];
    const float* be2 = (const float*)d_in[21];
    float* out = (float*)d_out;

    float* ws  = (float*)d_ws;
    float* s    = ws;                       // 8192*256 fp32
    float* pos  = ws + 2097152;             // 8192*3 (ping)
    short* e    = (short*)(ws + 2121728);   // 8192*31*32 bf16
    short* wb   = (short*)(ws + 6184960);   // weight images (1,175,424 shorts)
    short* sbf  = (short*)(ws + 6772672);   // 8192*256 bf16 mirror of s
    short* SAh  = (short*)(ws + 10248192);  // 8192*256 bf16
    short* SBh  = (short*)(ws + 12345344);  // 8192*256 bf16
    short* Hh   = (short*)(ws + 14442496);  // 8192*256 bf16 (Uh reuse)
    float* pos2 = ws + 16539648;            // 8192*3 (pong)
    short* tmph = SAh;                      // reuse after layers
    short* Uh   = Hh;                       // reuse after layers

    prep_weights<<<1024, 256, 0, stream>>>(gW1, gW2, Wh1, We1, We2, wb);
    node_init2<<<N_MOLS, 256, 0, stream>>>(x, z, rot, Wam, bam, s, sbf, pos);
    edge_init2<<<NN, 256, 0, stream>>>(ea, Wbm, bbm, e);

    float* pbuf[2] = { pos, pos2 };
    for (int l = 0; l < LAYERS_; ++l) {
        const float* b1 = gb1 + l * 256;
        const float* b2 = gb2 + l * 353;
        gemm_dual2<<<dim3(8, 64), 256, 0, stream>>>(
            sbf, wb + OFF_T1 + (size_t)l * 131072, SAh, SBh);
        edge_mfma<<<2 * N_MOLS, 512, 0, stream>>>(
            SAh, SBh, pbuf[l & 1], pbuf[(l + 1) & 1], e,
            wb + OFF_W1CG + l * 8192, wb + OFF_W1DA + l * 512,
            wb + OFF_W2P + l * 256, wb + OFF_W2EI + l * 8192,
            wb + OFF_W2ST + (size_t)l * 65536,
            b1, b2, s, sbf);
    }
    float* posF = pbuf[LAYERS_ & 1];

    gemm_mfma<1,1><<<dim3(4, 64), 256, 0, stream>>>(
        sbf, wb + OFF_WH1T, tmph, bh1, 256, 256, 1.f);
    atoms_kernel<<<512, 256, 0, stream>>>(tmph, Wh2, bh2, out);

    gemm_mfma<0,1><<<dim3(2, 64), 256, 0, stream>>>(
        sbf, wb + OFF_WE1T, Uh, nullptr, 256, 128, 1.f);
    bond_mfma<<<2 * N_MOLS, 512, 0, stream>>>(
        Uh, posF, e, wb + OFF_WE1CG, wb + OFF_WD, wb + OFF_WE2I,
        be1, be2, out + 131072);

    pos_copy<<<96, 256, 0, stream>>>(posF, out + 131072 + 1269760);
}